// Round 1
// baseline (534.254 us; speedup 1.0000x reference)
//
#include <hip/hip_runtime.h>
#include <hip/hip_bf16.h>
#include <math.h>

typedef __bf16 bf16_t;
typedef __bf16 bf16x4 __attribute__((ext_vector_type(4)));
typedef __bf16 bf16x8 __attribute__((ext_vector_type(8)));
typedef float  f32x4  __attribute__((ext_vector_type(4)));

#define LOG2E  1.4426950408889634f
#define QSCALE 0.04419417382415922f   /* 1/sqrt(512), folded into Wq/bq */

static __device__ __forceinline__ f32x4 mfma16(bf16x8 a, bf16x8 b, f32x4 c) {
    return __builtin_amdgcn_mfma_f32_16x16x32_bf16(a, b, c, 0, 0, 0);
}

// ---------------- staging ----------------

__global__ void k_stage_x(const float* __restrict__ x, bf16_t* __restrict__ xb) {
    int i = (blockIdx.x * blockDim.x + threadIdx.x) * 4;
    f32x4 v = *(const f32x4*)(x + i);
    bf16x4 o;
    o[0] = (bf16_t)v[0]; o[1] = (bf16_t)v[1]; o[2] = (bf16_t)v[2]; o[3] = (bf16_t)v[3];
    *(bf16x4*)(xb + i) = o;
}

// Wcat[n][d], n in [0,2560): per head 320 cols = 128 q | 128 k | 64 v. Transposed
// from W*[h][d][c] so GEMM B-fragments are contiguous in d. Scale folded into q.
__global__ void k_stage_w(const float* __restrict__ Wq, const float* __restrict__ Wk,
                          const float* __restrict__ Wv, bf16_t* __restrict__ Wcat) {
    int idx = blockIdx.x * blockDim.x + threadIdx.x;   // 2560*128
    int n = idx >> 7;
    int d = (idx & 127) * 4;
    int h = n / 320, r = n % 320;
    const float* src; int col, stride; float sc = 1.0f;
    if (r < 128)      { src = Wq + h * 512 * 128; col = r;       stride = 128; sc = QSCALE; }
    else if (r < 256) { src = Wk + h * 512 * 128; col = r - 128; stride = 128; }
    else              { src = Wv + h * 512 * 64;  col = r - 256; stride = 64;  }
    bf16x4 o;
    #pragma unroll
    for (int e = 0; e < 4; e++) o[e] = (bf16_t)(src[(d + e) * stride + col] * sc);
    *(bf16x4*)(Wcat + n * 512 + d) = o;
}

__global__ void k_stage_bias(const float* __restrict__ bq, const float* __restrict__ bk,
                             const float* __restrict__ bv, float* __restrict__ bcat) {
    int n = blockIdx.x * blockDim.x + threadIdx.x;
    if (n >= 2560) return;
    int h = n / 320, r = n % 320;
    float v;
    if (r < 128)      v = bq[h * 128 + r] * QSCALE;
    else if (r < 256) v = bk[h * 128 + r - 128];
    else              v = bv[h * 64 + r - 256];
    bcat[n] = v;
}

// Wot[dout][hv] = Wo[hv][dout]  (transpose so B-fragments contiguous in hv)
__global__ void k_stage_wo(const float* __restrict__ Wo, bf16_t* __restrict__ Wot) {
    int idx = blockIdx.x * blockDim.x + threadIdx.x;   // 512*128
    int n = idx >> 7;
    int d = (idx & 127) * 4;
    bf16x4 o;
    #pragma unroll
    for (int e = 0; e < 4; e++) o[e] = (bf16_t)Wo[(d + e) * 512 + n];
    *(bf16x4*)(Wot + n * 512 + d) = o;
}

// ---------------- QKV projection GEMM ----------------
// [4096,512] x [512,2560] via 16x16x32 MFMA; one wave = 16x16 output tile.
// Writes Q (scaled, bf16), K (bf16) row-major [h][4096][128]; V transposed [h][64][4096].
__global__ __launch_bounds__(256) void k_gemm_qkv(
        const bf16_t* __restrict__ xb, const bf16_t* __restrict__ Wcat,
        const float* __restrict__ bcat,
        bf16_t* __restrict__ Qb, bf16_t* __restrict__ Kb, bf16_t* __restrict__ Vt) {
    int lane = threadIdx.x & 63, wv = threadIdx.x >> 6;
    int rbase = blockIdx.x * 64 + wv * 16;
    int cbase = blockIdx.y * 16;
    int row = lane & 15, g = lane >> 4;

    const bf16_t* ap = xb + (rbase + row) * 512 + g * 8;
    const bf16_t* bp = Wcat + (cbase + row) * 512 + g * 8;
    f32x4 acc = {0.f, 0.f, 0.f, 0.f};
    #pragma unroll
    for (int kk = 0; kk < 512; kk += 32)
        acc = mfma16(*(const bf16x8*)(ap + kk), *(const bf16x8*)(bp + kk), acc);

    int n = cbase + row;           // D col = lane&15
    float bias = bcat[n];
    int h = n / 320, r = n % 320;
    #pragma unroll
    for (int i = 0; i < 4; i++) {
        int rr = rbase + g * 4 + i;   // D row = (lane>>4)*4 + i
        float val = acc[i] + bias;
        if (r < 128)      Qb[(h * 4096 + rr) * 128 + r]        = (bf16_t)val;
        else if (r < 256) Kb[(h * 4096 + rr) * 128 + (r - 128)] = (bf16_t)val;
        else              Vt[(h * 64 + (r - 256)) * 4096 + rr]  = (bf16_t)val;
    }
}

// ---------------- flash attention ----------------
// 1 wave = 16 q-rows of one head; loop keys in 32-tiles; fp32 online softmax;
// P re-layout to MFMA A-fragment via per-wave LDS tile [16][36] (padded stride).
__global__ __launch_bounds__(256) void k_attn(
        const bf16_t* __restrict__ Qb, const bf16_t* __restrict__ Kb,
        const bf16_t* __restrict__ Vt, bf16_t* __restrict__ Cb) {
    __shared__ __align__(16) float p_lds[4][16][36];
    int lane = threadIdx.x & 63, wv = threadIdx.x >> 6;
    int h = blockIdx.y;
    int qbase = blockIdx.x * 64 + wv * 16;
    int row = lane & 15, g = lane >> 4;

    const bf16_t* Qh = Qb + h * 4096 * 128;
    const bf16_t* Kh = Kb + h * 4096 * 128;
    const bf16_t* Vh = Vt + h * 64 * 4096;

    bf16x8 qf[4];
    #pragma unroll
    for (int c = 0; c < 4; c++)
        qf[c] = *(const bf16x8*)(Qh + (qbase + row) * 128 + c * 32 + g * 8);

    float m[4], l[4];
    f32x4 oacc[4];
    #pragma unroll
    for (int i = 0; i < 4; i++) { m[i] = -1e30f; l[i] = 0.f; }
    #pragma unroll
    for (int c = 0; c < 4; c++) oacc[c] = (f32x4){0.f, 0.f, 0.f, 0.f};

    for (int t0 = 0; t0 < 4096; t0 += 32) {
        // S = Q K^T for 32 keys (two 16-key column tiles)
        f32x4 s0 = {0.f,0.f,0.f,0.f}, s1 = {0.f,0.f,0.f,0.f};
        const bf16_t* K0 = Kh + (t0 + row) * 128 + g * 8;
        const bf16_t* K1 = K0 + 16 * 128;
        #pragma unroll
        for (int c = 0; c < 4; c++) s0 = mfma16(qf[c], *(const bf16x8*)(K0 + c * 32), s0);
        #pragma unroll
        for (int c = 0; c < 4; c++) s1 = mfma16(qf[c], *(const bf16x8*)(K1 + c * 32), s1);

        // online softmax (rows live in regs i, 16 key-cols across lanes of each 16-group)
        float p0[4], p1[4], al[4];
        #pragma unroll
        for (int i = 0; i < 4; i++) {
            float v = fmaxf(s0[i], s1[i]);
            v = fmaxf(v, __shfl_xor(v, 1));
            v = fmaxf(v, __shfl_xor(v, 2));
            v = fmaxf(v, __shfl_xor(v, 4));
            v = fmaxf(v, __shfl_xor(v, 8));
            float mn = fmaxf(m[i], v);
            al[i] = exp2f((m[i] - mn) * LOG2E);
            p0[i] = exp2f((s0[i] - mn) * LOG2E);
            p1[i] = exp2f((s1[i] - mn) * LOG2E);
            m[i] = mn;
            float ps = p0[i] + p1[i];
            ps += __shfl_xor(ps, 1);
            ps += __shfl_xor(ps, 2);
            ps += __shfl_xor(ps, 4);
            ps += __shfl_xor(ps, 8);
            l[i] = l[i] * al[i] + ps;
        }
        #pragma unroll
        for (int c = 0; c < 4; c++)
            #pragma unroll
            for (int i = 0; i < 4; i++) oacc[c][i] *= al[i];

        // P: D-layout -> A-fragment layout via LDS (stride 36 => 2-way banks, 16B aligned)
        #pragma unroll
        for (int i = 0; i < 4; i++) {
            p_lds[wv][g * 4 + i][row]      = p0[i];
            p_lds[wv][g * 4 + i][16 + row] = p1[i];
        }
        f32x4 f0 = *(const f32x4*)&p_lds[wv][row][g * 8];
        f32x4 f1 = *(const f32x4*)&p_lds[wv][row][g * 8 + 4];
        bf16x8 pa;
        #pragma unroll
        for (int e = 0; e < 4; e++) { pa[e] = (bf16_t)f0[e]; pa[4 + e] = (bf16_t)f1[e]; }

        // O += P V  (V transposed: contiguous t)
        #pragma unroll
        for (int c = 0; c < 4; c++) {
            bf16x8 vf = *(const bf16x8*)(Vh + (c * 16 + row) * 4096 + t0 + g * 8);
            oacc[c] = mfma16(pa, vf, oacc[c]);
        }
    }

    // epilogue: normalize, write concat [4096][512] bf16
    #pragma unroll
    for (int c = 0; c < 4; c++)
        #pragma unroll
        for (int i = 0; i < 4; i++)
            Cb[(qbase + g * 4 + i) * 512 + h * 64 + c * 16 + row] =
                (bf16_t)(oacc[c][i] / l[i]);
}

// ---------------- output projection ----------------
__global__ __launch_bounds__(256) void k_gemm_out(
        const bf16_t* __restrict__ Cb, const bf16_t* __restrict__ Wot,
        const float* __restrict__ bo, float* __restrict__ out) {
    int lane = threadIdx.x & 63, wv = threadIdx.x >> 6;
    int rbase = blockIdx.x * 64 + wv * 16;
    int cbase = blockIdx.y * 16;
    int row = lane & 15, g = lane >> 4;

    const bf16_t* ap = Cb + (rbase + row) * 512 + g * 8;
    const bf16_t* bp = Wot + (cbase + row) * 512 + g * 8;
    f32x4 acc = {0.f, 0.f, 0.f, 0.f};
    #pragma unroll
    for (int kk = 0; kk < 512; kk += 32)
        acc = mfma16(*(const bf16x8*)(ap + kk), *(const bf16x8*)(bp + kk), acc);

    float bias = bo[cbase + row];
    #pragma unroll
    for (int i = 0; i < 4; i++)
        out[(rbase + g * 4 + i) * 512 + cbase + row] = acc[i] + bias;
}

// ---------------- launch ----------------
extern "C" void kernel_launch(void* const* d_in, const int* in_sizes, int n_in,
                              void* d_out, int out_size, void* d_ws, size_t ws_size,
                              hipStream_t stream) {
    const float* x  = (const float*)d_in[0];
    const float* Wq = (const float*)d_in[1];
    const float* bq = (const float*)d_in[2];
    const float* Wk = (const float*)d_in[3];
    const float* bk = (const float*)d_in[4];
    const float* Wv = (const float*)d_in[5];
    const float* bv = (const float*)d_in[6];
    const float* Wo = (const float*)d_in[7];
    const float* bo = (const float*)d_in[8];
    float* out = (float*)d_out;

    char* ws = (char*)d_ws;
    bf16_t* xb   = (bf16_t*)(ws + 0);          // 4096*512*2      = 4,194,304
    bf16_t* Wcat = (bf16_t*)(ws + 4194304);    // 2560*512*2      = 2,621,440
    bf16_t* Qb   = (bf16_t*)(ws + 6815744);    // 8*4096*128*2    = 8,388,608
    bf16_t* Kb   = (bf16_t*)(ws + 15204352);   // 8*4096*128*2    = 8,388,608
    bf16_t* Vt   = (bf16_t*)(ws + 23592960);   // 8*64*4096*2     = 4,194,304
    bf16_t* Cb   = (bf16_t*)(ws + 27787264);   // 4096*512*2      = 4,194,304
    bf16_t* Wot  = (bf16_t*)(ws + 31981568);   // 512*512*2       = 524,288
    float*  bcat = (float*)(ws + 32505856);    // 2560*4          = 10,240

    hipLaunchKernelGGL(k_stage_x,    dim3(2048), dim3(256), 0, stream, x, xb);
    hipLaunchKernelGGL(k_stage_w,    dim3(1280), dim3(256), 0, stream, Wq, Wk, Wv, Wcat);
    hipLaunchKernelGGL(k_stage_bias, dim3(10),   dim3(256), 0, stream, bq, bk, bv, bcat);
    hipLaunchKernelGGL(k_stage_wo,   dim3(256),  dim3(256), 0, stream, Wo, Wot);
    hipLaunchKernelGGL(k_gemm_qkv,   dim3(64, 160), dim3(256), 0, stream, xb, Wcat, bcat, Qb, Kb, Vt);
    hipLaunchKernelGGL(k_attn,       dim3(64, 8),   dim3(256), 0, stream, Qb, Kb, Vt, Cb);
    hipLaunchKernelGGL(k_gemm_out,   dim3(64, 32),  dim3(256), 0, stream, Cb, Wot, bo, out);
}

// Round 2
// 311.745 us; speedup vs baseline: 1.7138x; 1.7138x over previous
//
#include <hip/hip_runtime.h>
#include <hip/hip_bf16.h>
#include <math.h>

typedef __bf16 bf16_t;
typedef __bf16 bf16x4 __attribute__((ext_vector_type(4)));
typedef __bf16 bf16x8 __attribute__((ext_vector_type(8)));
typedef float  f32x4  __attribute__((ext_vector_type(4)));

#define LOG2E  1.4426950408889634f
#define QSCALE 0.04419417382415922f   /* 1/sqrt(512), folded into Wq/bq */

static __device__ __forceinline__ f32x4 mfma16(bf16x8 a, bf16x8 b, f32x4 c) {
    return __builtin_amdgcn_mfma_f32_16x16x32_bf16(a, b, c, 0, 0, 0);
}

// async global->LDS, 16B per lane; lds dest = wave-uniform base + lane*16
static __device__ __forceinline__ void gload16(void* lds, const void* g) {
    __builtin_amdgcn_global_load_lds(
        (const __attribute__((address_space(1))) unsigned int*)g,
        (__attribute__((address_space(3))) unsigned int*)lds, 16, 0, 0);
}

// ---------------- staging ----------------

__global__ void k_stage_x(const float* __restrict__ x, bf16_t* __restrict__ xb) {
    int i = (blockIdx.x * blockDim.x + threadIdx.x) * 4;
    f32x4 v = *(const f32x4*)(x + i);
    bf16x4 o;
    o[0] = (bf16_t)v[0]; o[1] = (bf16_t)v[1]; o[2] = (bf16_t)v[2]; o[3] = (bf16_t)v[3];
    *(bf16x4*)(xb + i) = o;
}

__global__ void k_stage_w(const float* __restrict__ Wq, const float* __restrict__ Wk,
                          const float* __restrict__ Wv, bf16_t* __restrict__ Wcat) {
    int idx = blockIdx.x * blockDim.x + threadIdx.x;   // 2560*128
    int n = idx >> 7;
    int d = (idx & 127) * 4;
    int h = n / 320, r = n % 320;
    const float* src; int col, stride; float sc = 1.0f;
    if (r < 128)      { src = Wq + h * 512 * 128; col = r;       stride = 128; sc = QSCALE; }
    else if (r < 256) { src = Wk + h * 512 * 128; col = r - 128; stride = 128; }
    else              { src = Wv + h * 512 * 64;  col = r - 256; stride = 64;  }
    bf16x4 o;
    #pragma unroll
    for (int e = 0; e < 4; e++) o[e] = (bf16_t)(src[(d + e) * stride + col] * sc);
    *(bf16x4*)(Wcat + n * 512 + d) = o;
}

__global__ void k_stage_bias(const float* __restrict__ bq, const float* __restrict__ bk,
                             const float* __restrict__ bv, float* __restrict__ bcat) {
    int n = blockIdx.x * blockDim.x + threadIdx.x;
    if (n >= 2560) return;
    int h = n / 320, r = n % 320;
    float v;
    if (r < 128)      v = bq[h * 128 + r] * QSCALE;
    else if (r < 256) v = bk[h * 128 + r - 128];
    else              v = bv[h * 64 + r - 256];
    bcat[n] = v;
}

__global__ void k_stage_wo(const float* __restrict__ Wo, bf16_t* __restrict__ Wot) {
    int idx = blockIdx.x * blockDim.x + threadIdx.x;   // 512*128
    int n = idx >> 7;
    int d = (idx & 127) * 4;
    bf16x4 o;
    #pragma unroll
    for (int e = 0; e < 4; e++) o[e] = (bf16_t)Wo[(d + e) * 512 + n];
    *(bf16x4*)(Wot + n * 512 + d) = o;
}

// ---------------- QKV projection GEMM ----------------
// wave = 16 rows x 64 cols (4 B-frags per A-frag). grid (64, 40).
__global__ __launch_bounds__(256) void k_gemm_qkv(
        const bf16_t* __restrict__ xb, const bf16_t* __restrict__ Wcat,
        const float* __restrict__ bcat,
        bf16_t* __restrict__ Qb, bf16_t* __restrict__ Kb, bf16_t* __restrict__ Vt) {
    int lane = threadIdx.x & 63, wv = threadIdx.x >> 6;
    int rbase = blockIdx.x * 64 + wv * 16;
    int cbase = blockIdx.y * 64;
    int row = lane & 15, g = lane >> 4;

    const bf16_t* ap = xb + (rbase + row) * 512 + g * 8;
    const bf16_t* bp = Wcat + (cbase + row) * 512 + g * 8;
    f32x4 acc[4];
    #pragma unroll
    for (int cc = 0; cc < 4; cc++) acc[cc] = (f32x4){0.f,0.f,0.f,0.f};
    #pragma unroll 4
    for (int kk = 0; kk < 512; kk += 32) {
        bf16x8 a = *(const bf16x8*)(ap + kk);
        #pragma unroll
        for (int cc = 0; cc < 4; cc++)
            acc[cc] = mfma16(a, *(const bf16x8*)(bp + cc * 16 * 512 + kk), acc[cc]);
    }

    #pragma unroll
    for (int cc = 0; cc < 4; cc++) {
        int n = cbase + cc * 16 + row;
        float bias = bcat[n];
        int h = n / 320, r = n % 320;
        #pragma unroll
        for (int i = 0; i < 4; i++) {
            int rr = rbase + g * 4 + i;
            float val = acc[cc][i] + bias;
            if (r < 128)      Qb[(h * 4096 + rr) * 128 + r]         = (bf16_t)val;
            else if (r < 256) Kb[(h * 4096 + rr) * 128 + (r - 128)] = (bf16_t)val;
            else              Vt[(h * 64 + (r - 256)) * 4096 + rr]  = (bf16_t)val;
        }
    }
}

// ---------------- flash attention ----------------
// block = 4 waves, 64 q-rows (16/wave), one head, one key-split.
// KVB=64: K tile double-buffered in LDS (XOR-swizzled, global_load_lds),
// V from global (Vt layout), P repack via per-wave LDS [16][68].
static __device__ __forceinline__ void stage_k(bf16_t* kbuf, const bf16_t* Kh,
                                               int kt, int wv, int lane) {
    #pragma unroll
    for (int j = 0; j < 4; ++j) {
        int local = wv * 16 + j * 4 + (lane >> 4);      // key row 0..63
        int physcol = (lane & 15) << 4;                 // byte col in 256B row
        const char* src = (const char*)(Kh + (size_t)(kt + local) * 128)
                        + (physcol ^ ((local & 7) << 4));
        gload16(kbuf + (wv * 16 + j * 4) * 128, src);   // uniform base; hw adds lane*16B
    }
}

__global__ __launch_bounds__(256, 4) void k_attn(
        const bf16_t* __restrict__ Qb, const bf16_t* __restrict__ Kb,
        const bf16_t* __restrict__ Vt, bf16_t* __restrict__ Cb,
        float* __restrict__ Opart, float* __restrict__ MLpart, int nkeys) {
    __shared__ __align__(16) bf16_t k_lds[2][64 * 128];
    __shared__ __align__(16) float p_lds[4][16][68];

    const int lane = threadIdx.x & 63, wv = threadIdx.x >> 6;
    const int row = lane & 15, g = lane >> 4;
    const int h = blockIdx.y;
    const int q0 = blockIdx.x * 64 + wv * 16;
    const int split = blockIdx.z;
    const int kstart = split * nkeys;
    const int ntiles = nkeys >> 6;

    const bf16_t* Qh = Qb + h * 4096 * 128;
    const bf16_t* Kh = Kb + h * 4096 * 128;
    const bf16_t* Vh = Vt + h * 64 * 4096;

    bf16x8 qf[4];
    #pragma unroll
    for (int c = 0; c < 4; c++)
        qf[c] = *(const bf16x8*)(Qh + (q0 + row) * 128 + c * 32 + g * 8);

    float m[4], l[4];
    f32x4 oacc[4];
    #pragma unroll
    for (int i = 0; i < 4; i++) { m[i] = -1e30f; l[i] = 0.f; }
    #pragma unroll
    for (int c = 0; c < 4; c++) oacc[c] = (f32x4){0.f,0.f,0.f,0.f};

    stage_k(&k_lds[0][0], Kh, kstart, wv, lane);
    __syncthreads();

    for (int it = 0; it < ntiles; ++it) {
        const int cur = it & 1;
        const int kt = kstart + it * 64;
        if (it + 1 < ntiles) stage_k(&k_lds[cur ^ 1][0], Kh, kt + 64, wv, lane);

        // S = Q K^T for 64 keys
        f32x4 s[4];
        #pragma unroll
        for (int t = 0; t < 4; t++) s[t] = (f32x4){0.f,0.f,0.f,0.f};
        #pragma unroll
        for (int t = 0; t < 4; t++) {
            const bf16_t* kr = &k_lds[cur][(t * 16 + row) * 128];
            #pragma unroll
            for (int c = 0; c < 4; c++) {
                int offb = (c * 64 + g * 16) ^ ((row & 7) << 4);   // swizzled byte col
                bf16x8 kf = *(const bf16x8*)(kr + (offb >> 1));
                s[t] = mfma16(qf[c], kf, s[t]);
            }
        }

        // online softmax over 64 keys (in-lane over 4 regs, then 4 shuffle rounds)
        float p[4][4], alv[4];
        #pragma unroll
        for (int i = 0; i < 4; i++) {
            float mx = fmaxf(fmaxf(s[0][i], s[1][i]), fmaxf(s[2][i], s[3][i]));
            mx = fmaxf(mx, __shfl_xor(mx, 1));
            mx = fmaxf(mx, __shfl_xor(mx, 2));
            mx = fmaxf(mx, __shfl_xor(mx, 4));
            mx = fmaxf(mx, __shfl_xor(mx, 8));
            float mn = fmaxf(m[i], mx);
            alv[i] = __builtin_amdgcn_exp2f((m[i] - mn) * LOG2E);
            #pragma unroll
            for (int t = 0; t < 4; t++)
                p[t][i] = __builtin_amdgcn_exp2f((s[t][i] - mn) * LOG2E);
            m[i] = mn;
            float ps = (p[0][i] + p[1][i]) + (p[2][i] + p[3][i]);
            ps += __shfl_xor(ps, 1);
            ps += __shfl_xor(ps, 2);
            ps += __shfl_xor(ps, 4);
            ps += __shfl_xor(ps, 8);
            l[i] = l[i] * alv[i] + ps;
        }
        #pragma unroll
        for (int c = 0; c < 4; c++)
            #pragma unroll
            for (int i = 0; i < 4; i++) oacc[c][i] *= alv[i];

        // P: D-layout (q = g*4+i) -> A-frag layout (q = lane&15) via LDS
        #pragma unroll
        for (int t = 0; t < 4; t++)
            #pragma unroll
            for (int i = 0; i < 4; i++)
                p_lds[wv][g * 4 + i][t * 16 + row] = p[t][i];

        bf16x8 pa[2];
        #pragma unroll
        for (int t2 = 0; t2 < 2; t2++) {
            f32x4 f0 = *(const f32x4*)&p_lds[wv][row][t2 * 32 + g * 8];
            f32x4 f1 = *(const f32x4*)&p_lds[wv][row][t2 * 32 + g * 8 + 4];
            bf16x8 tmp;
            #pragma unroll
            for (int e = 0; e < 4; e++) { tmp[e] = (bf16_t)f0[e]; tmp[4 + e] = (bf16_t)f1[e]; }
            pa[t2] = tmp;
        }

        #pragma unroll
        for (int c = 0; c < 4; c++)
            #pragma unroll
            for (int t2 = 0; t2 < 2; t2++) {
                bf16x8 vf = *(const bf16x8*)(Vh + (c * 16 + row) * 4096 + kt + t2 * 32 + g * 8);
                oacc[c] = mfma16(pa[t2], vf, oacc[c]);
            }

        __syncthreads();   // drains vmcnt (prefetch) + lgkm; buffers swap safely
    }

    if (gridDim.z == 1) {
        #pragma unroll
        for (int c = 0; c < 4; c++)
            #pragma unroll
            for (int i = 0; i < 4; i++)
                Cb[(q0 + g * 4 + i) * 512 + h * 64 + c * 16 + row] =
                    (bf16_t)(oacc[c][i] / l[i]);
    } else {
        float* Op = Opart + ((size_t)(split * 8 + h) * 4096 + q0) * 64;
        #pragma unroll
        for (int c = 0; c < 4; c++)
            #pragma unroll
            for (int i = 0; i < 4; i++)
                Op[(g * 4 + i) * 64 + c * 16 + row] = oacc[c][i];
        if (row == 0) {
            float* mlp = MLpart + ((size_t)(split * 8 + h) * 4096 + q0) * 2;
            #pragma unroll
            for (int i = 0; i < 4; i++) {
                mlp[(g * 4 + i) * 2]     = m[i];
                mlp[(g * 4 + i) * 2 + 1] = l[i];
            }
        }
    }
}

// combine 2 key-splits: O = (O0*e0 + O1*e1) / (l0*e0 + l1*e1)
__global__ void k_merge(const float* __restrict__ Opart, const float* __restrict__ MLpart,
                        bf16_t* __restrict__ Cb) {
    int idx = blockIdx.x * 256 + threadIdx.x;   // 4096*512
    int q = idx >> 9, hv = idx & 511;
    int h = hv >> 6, dv = hv & 63;
    const float* ml0 = MLpart + ((size_t)h * 4096 + q) * 2;
    const float* ml1 = MLpart + ((size_t)(8 + h) * 4096 + q) * 2;
    float m0 = ml0[0], l0 = ml0[1];
    float m1 = ml1[0], l1 = ml1[1];
    float M = fmaxf(m0, m1);
    float e0 = __builtin_amdgcn_exp2f((m0 - M) * LOG2E);
    float e1 = __builtin_amdgcn_exp2f((m1 - M) * LOG2E);
    float O0 = Opart[((size_t)h * 4096 + q) * 64 + dv];
    float O1 = Opart[((size_t)(8 + h) * 4096 + q) * 64 + dv];
    Cb[q * 512 + hv] = (bf16_t)((O0 * e0 + O1 * e1) / (l0 * e0 + l1 * e1));
}

// ---------------- output projection ----------------
__global__ __launch_bounds__(256) void k_gemm_out(
        const bf16_t* __restrict__ Cb, const bf16_t* __restrict__ Wot,
        const float* __restrict__ bo, float* __restrict__ out) {
    int lane = threadIdx.x & 63, wv = threadIdx.x >> 6;
    int rbase = blockIdx.x * 64 + wv * 16;
    int cbase = blockIdx.y * 64;
    int row = lane & 15, g = lane >> 4;

    const bf16_t* ap = Cb + (rbase + row) * 512 + g * 8;
    const bf16_t* bp = Wot + (cbase + row) * 512 + g * 8;
    f32x4 acc[4];
    #pragma unroll
    for (int cc = 0; cc < 4; cc++) acc[cc] = (f32x4){0.f,0.f,0.f,0.f};
    #pragma unroll 4
    for (int kk = 0; kk < 512; kk += 32) {
        bf16x8 a = *(const bf16x8*)(ap + kk);
        #pragma unroll
        for (int cc = 0; cc < 4; cc++)
            acc[cc] = mfma16(a, *(const bf16x8*)(bp + cc * 16 * 512 + kk), acc[cc]);
    }

    #pragma unroll
    for (int cc = 0; cc < 4; cc++) {
        float bias = bo[cbase + cc * 16 + row];
        #pragma unroll
        for (int i = 0; i < 4; i++)
            out[(rbase + g * 4 + i) * 512 + cbase + cc * 16 + row] = acc[cc][i] + bias;
    }
}

// ---------------- launch ----------------
extern "C" void kernel_launch(void* const* d_in, const int* in_sizes, int n_in,
                              void* d_out, int out_size, void* d_ws, size_t ws_size,
                              hipStream_t stream) {
    const float* x  = (const float*)d_in[0];
    const float* Wq = (const float*)d_in[1];
    const float* bq = (const float*)d_in[2];
    const float* Wk = (const float*)d_in[3];
    const float* bk = (const float*)d_in[4];
    const float* Wv = (const float*)d_in[5];
    const float* bv = (const float*)d_in[6];
    const float* Wo = (const float*)d_in[7];
    const float* bo = (const float*)d_in[8];
    float* out = (float*)d_out;

    char* ws = (char*)d_ws;
    bf16_t* xb    = (bf16_t*)(ws + 0);          // 4,194,304
    bf16_t* Wcat  = (bf16_t*)(ws + 4194304);    // 2,621,440
    bf16_t* Qb    = (bf16_t*)(ws + 6815744);    // 8,388,608
    bf16_t* Kb    = (bf16_t*)(ws + 15204352);   // 8,388,608
    bf16_t* Vt    = (bf16_t*)(ws + 23592960);   // 4,194,304
    bf16_t* Cb    = (bf16_t*)(ws + 27787264);   // 4,194,304
    bf16_t* Wot   = (bf16_t*)(ws + 31981568);   // 524,288
    float*  bcat  = (float*)(ws + 32505856);    // 10,240
    float*  Opart = (float*)(ws + 32516096);    // 2*8*4096*64*4 = 16,777,216
    float*  MLprt = (float*)(ws + 49293312);    // 2*8*4096*2*4  = 524,288
                                                // total (splits=2): 49,817,600
    const size_t NEED2 = 49817600;
    int splits = (ws_size >= NEED2) ? 2 : 1;

    hipLaunchKernelGGL(k_stage_x,    dim3(2048), dim3(256), 0, stream, x, xb);
    hipLaunchKernelGGL(k_stage_w,    dim3(1280), dim3(256), 0, stream, Wq, Wk, Wv, Wcat);
    hipLaunchKernelGGL(k_stage_bias, dim3(10),   dim3(256), 0, stream, bq, bk, bv, bcat);
    hipLaunchKernelGGL(k_stage_wo,   dim3(256),  dim3(256), 0, stream, Wo, Wot);
    hipLaunchKernelGGL(k_gemm_qkv,   dim3(64, 40),        dim3(256), 0, stream, xb, Wcat, bcat, Qb, Kb, Vt);
    hipLaunchKernelGGL(k_attn,       dim3(64, 8, splits), dim3(256), 0, stream, Qb, Kb, Vt, Cb, Opart, MLprt, 4096 / splits);
    if (splits == 2)
        hipLaunchKernelGGL(k_merge,  dim3(8192), dim3(256), 0, stream, Opart, MLprt, Cb);
    hipLaunchKernelGGL(k_gemm_out,   dim3(64, 8), dim3(256), 0, stream, Cb, Wot, bo, out);
}

// Round 3
// 194.831 us; speedup vs baseline: 2.7421x; 1.6001x over previous
//
#include <hip/hip_runtime.h>
#include <hip/hip_bf16.h>
#include <math.h>

typedef __bf16 bf16_t;
typedef __bf16 bf16x4 __attribute__((ext_vector_type(4)));
typedef __bf16 bf16x8 __attribute__((ext_vector_type(8)));
typedef float  f32x4  __attribute__((ext_vector_type(4)));

#define LOG2E   1.4426950408889634f
#define QSCALE  0.04419417382415922f            /* 1/sqrt(512) */
#define QS_TOT  (QSCALE * LOG2E)                /* folded into Wq/bq: scores in log2 units */
#define DEFER_THR 8.0f

static __device__ __forceinline__ f32x4 mfma16(bf16x8 a, bf16x8 b, f32x4 c) {
    return __builtin_amdgcn_mfma_f32_16x16x32_bf16(a, b, c, 0, 0, 0);
}

static __device__ __forceinline__ void gload16(void* lds, const void* g) {
    __builtin_amdgcn_global_load_lds(
        (const __attribute__((address_space(1))) unsigned int*)g,
        (__attribute__((address_space(3))) unsigned int*)lds, 16, 0, 0);
}

// ---------------- staging ----------------

__global__ void k_stage_x(const float* __restrict__ x, bf16_t* __restrict__ xb) {
    int i = (blockIdx.x * blockDim.x + threadIdx.x) * 4;
    f32x4 v = *(const f32x4*)(x + i);
    bf16x4 o;
    o[0] = (bf16_t)v[0]; o[1] = (bf16_t)v[1]; o[2] = (bf16_t)v[2]; o[3] = (bf16_t)v[3];
    *(bf16x4*)(xb + i) = o;
}

// LDS-tiled transpose: W*[h][d][c] (f32) -> Wcat[h*320 + part_off + c][d] (bf16)
__global__ void k_stage_wt(const float* __restrict__ Wq, const float* __restrict__ Wk,
                           const float* __restrict__ Wv, bf16_t* __restrict__ Wcat) {
    __shared__ float tl[64][65];
    int p = blockIdx.y;
    int bid = blockIdx.x;                    // 128
    int h = bid >> 4, rem = bid & 15, dt = rem >> 1, ct = rem & 1;
    if (p == 2 && ct) return;
    int cols = (p == 2) ? 64 : 128;
    const float* src = (p == 0 ? Wq : (p == 1 ? Wk : Wv)) + h * 512 * cols;
    int d0 = dt * 64, c0 = ct * 64;
    int cin = threadIdx.x & 63, rb = threadIdx.x >> 6;
    #pragma unroll
    for (int j = 0; j < 16; j++) {
        int dl = rb * 16 + j;
        tl[dl][cin] = src[(d0 + dl) * cols + c0 + cin];
    }
    __syncthreads();
    float sc = (p == 0) ? QS_TOT : 1.0f;
    int nl = threadIdx.x >> 2, dch = (threadIdx.x & 3) * 16;
    int n = h * 320 + p * 128 + c0 + nl;
    bf16_t* dst = Wcat + n * 512 + d0 + dch;
    #pragma unroll
    for (int e = 0; e < 16; e += 4) {
        bf16x4 o;
        #pragma unroll
        for (int q = 0; q < 4; q++) o[q] = (bf16_t)(tl[dch + e + q][nl] * sc);
        *(bf16x4*)(dst + e) = o;
    }
}

__global__ void k_stage_bias(const float* __restrict__ bq, const float* __restrict__ bk,
                             const float* __restrict__ bv, float* __restrict__ bcat) {
    int n = blockIdx.x * blockDim.x + threadIdx.x;
    if (n >= 2560) return;
    int h = n / 320, r = n % 320;
    float v;
    if (r < 128)      v = bq[h * 128 + r] * QS_TOT;
    else if (r < 256) v = bk[h * 128 + r - 128];
    else              v = bv[h * 64 + r - 256];
    bcat[n] = v;
}

// Wo[hv=512][dout=512] f32 -> Wot[dout][hv] bf16, LDS-tiled
__global__ void k_stage_wo_t(const float* __restrict__ Wo, bf16_t* __restrict__ Wot) {
    __shared__ float tl[64][65];
    int r0 = blockIdx.x * 64, c0 = blockIdx.y * 64;
    int cin = threadIdx.x & 63, rb = threadIdx.x >> 6;
    #pragma unroll
    for (int j = 0; j < 16; j++) {
        int rl = rb * 16 + j;
        tl[rl][cin] = Wo[(r0 + rl) * 512 + c0 + cin];
    }
    __syncthreads();
    int nl = threadIdx.x >> 2, dch = (threadIdx.x & 3) * 16;
    bf16_t* dst = Wot + (c0 + nl) * 512 + r0 + dch;
    #pragma unroll
    for (int e = 0; e < 16; e += 4) {
        bf16x4 o;
        #pragma unroll
        for (int q = 0; q < 4; q++) o[q] = (bf16_t)tl[dch + e + q][nl];
        *(bf16x4*)(dst + e) = o;
    }
}

// ---------------- QKV projection GEMM ----------------
// wave = 32 rows x 64 cols. grid (32, 40). V stored time-permuted for zero-shuffle PV.
__global__ __launch_bounds__(256) void k_gemm_qkv(
        const bf16_t* __restrict__ xb, const bf16_t* __restrict__ Wcat,
        const float* __restrict__ bcat,
        bf16_t* __restrict__ Qb, bf16_t* __restrict__ Kb, bf16_t* __restrict__ Vt) {
    int lane = threadIdx.x & 63, wv = threadIdx.x >> 6;
    int rbase = blockIdx.x * 128 + wv * 32;
    int cbase = blockIdx.y * 64;
    int row = lane & 15, g = lane >> 4;

    const bf16_t* ap = xb + (rbase + row) * 512 + g * 8;
    const bf16_t* bp = Wcat + (cbase + row) * 512 + g * 8;
    f32x4 acc[2][4];
    #pragma unroll
    for (int at = 0; at < 2; at++)
        #pragma unroll
        for (int cc = 0; cc < 4; cc++) acc[at][cc] = (f32x4){0.f,0.f,0.f,0.f};
    #pragma unroll 4
    for (int kk = 0; kk < 512; kk += 32) {
        bf16x8 a0 = *(const bf16x8*)(ap + kk);
        bf16x8 a1 = *(const bf16x8*)(ap + 16 * 512 + kk);
        #pragma unroll
        for (int cc = 0; cc < 4; cc++) {
            bf16x8 b = *(const bf16x8*)(bp + cc * 16 * 512 + kk);
            acc[0][cc] = mfma16(a0, b, acc[0][cc]);
            acc[1][cc] = mfma16(a1, b, acc[1][cc]);
        }
    }

    #pragma unroll
    for (int cc = 0; cc < 4; cc++) {
        int n = cbase + cc * 16 + row;
        float bias = bcat[n];
        int h = n / 320, r = n % 320;
        #pragma unroll
        for (int at = 0; at < 2; at++)
            #pragma unroll
            for (int i = 0; i < 4; i++) {
                int rr = rbase + at * 16 + g * 4 + i;
                float val = acc[at][cc][i] + bias;
                if (r < 128)      Qb[(h * 4096 + rr) * 128 + r]         = (bf16_t)val;
                else if (r < 256) Kb[(h * 4096 + rr) * 128 + (r - 128)] = (bf16_t)val;
                else {
                    // permuted time slot: key=16b+4gk+ik (within 32) -> 8gk+4b+ik
                    int cp = (rr & ~31) | (((rr >> 2) & 3) << 3) | (((rr >> 4) & 1) << 2) | (rr & 3);
                    Vt[(h * 64 + (r - 256)) * 4096 + cp] = (bf16_t)val;
                }
            }
    }
}

// ---------------- flash attention ----------------
// block = 4 waves x 32 q-rows = 128 q. Swapped QK^T (S^T in regs, lane&15 = q),
// in-lane softmax (log2 domain, defer-max), zero-shuffle PV via permuted Vt.
static __device__ __forceinline__ void stage_k(bf16_t* kbuf, const bf16_t* Kh,
                                               int kt, int wv, int lane) {
    #pragma unroll
    for (int j = 0; j < 4; ++j) {
        int local = wv * 16 + j * 4 + (lane >> 4);
        int physcol = (lane & 15) << 4;
        const char* src = (const char*)(Kh + (size_t)(kt + local) * 128)
                        + (physcol ^ ((local & 7) << 4));
        gload16(kbuf + (wv * 16 + j * 4) * 128, src);
    }
}

static __device__ __forceinline__ float vmax4(f32x4 v) {
    return fmaxf(fmaxf(v[0], v[1]), fmaxf(v[2], v[3]));
}

__global__ __launch_bounds__(256, 3) void k_attn(
        const bf16_t* __restrict__ Qb, const bf16_t* __restrict__ Kb,
        const bf16_t* __restrict__ Vt, bf16_t* __restrict__ Cb,
        float* __restrict__ Opart, float* __restrict__ MLpart, int nkeys) {
    __shared__ __align__(16) bf16_t k_lds[2][64 * 128];

    const int lane = threadIdx.x & 63, wv = threadIdx.x >> 6;
    const int qi = lane & 15, g = lane >> 4;

    // bijective XCD-chunked swizzle (nwg = 256*splits, %8==0)
    int nwg = 32 * 8 * gridDim.z, cpx = nwg >> 3;
    int wgid = blockIdx.x + 32 * (blockIdx.y + 8 * blockIdx.z);
    int wk = (wgid & 7) * cpx + (wgid >> 3);
    const int qb = wk & 31, h = (wk >> 5) & 7, split = wk >> 8;

    const int q0 = qb * 128 + wv * 32;
    const int kstart = split * nkeys;
    const int ntiles = nkeys >> 6;

    const bf16_t* Qh = Qb + h * 4096 * 128;
    const bf16_t* Kh = Kb + h * 4096 * 128;
    const bf16_t* Vh = Vt + h * 64 * 4096;

    bf16x8 qf[2][4];
    #pragma unroll
    for (int qt = 0; qt < 2; qt++)
        #pragma unroll
        for (int c = 0; c < 4; c++)
            qf[qt][c] = *(const bf16x8*)(Qh + (q0 + qt * 16 + qi) * 128 + c * 32 + g * 8);

    float m[2] = {-1e30f, -1e30f}, l[2] = {0.f, 0.f};
    f32x4 oacc[2][4];
    #pragma unroll
    for (int qt = 0; qt < 2; qt++)
        #pragma unroll
        for (int c = 0; c < 4; c++) oacc[qt][c] = (f32x4){0.f,0.f,0.f,0.f};

    stage_k(&k_lds[0][0], Kh, kstart, wv, lane);
    __syncthreads();

    for (int it = 0; it < ntiles; ++it) {
        const int cur = it & 1;
        const int kt = kstart + it * 64;
        if (it + 1 < ntiles) stage_k(&k_lds[cur ^ 1][0], Kh, kt + 64, wv, lane);

        // S^T = K Q^T : lane holds 16 scores (keys 16t+4g+i) for q = q0+qt*16+qi
        f32x4 s[2][4];
        #pragma unroll
        for (int qt = 0; qt < 2; qt++)
            #pragma unroll
            for (int t = 0; t < 4; t++) s[qt][t] = (f32x4){0.f,0.f,0.f,0.f};
        __builtin_amdgcn_s_setprio(1);
        #pragma unroll
        for (int t = 0; t < 4; t++) {
            const bf16_t* kr = &k_lds[cur][(t * 16 + qi) * 128];
            #pragma unroll
            for (int c = 0; c < 4; c++) {
                int offb = (c * 64 + g * 16) ^ ((qi & 7) << 4);
                bf16x8 kf = *(const bf16x8*)(kr + (offb >> 1));
                s[0][t] = mfma16(kf, qf[0][c], s[0][t]);
                s[1][t] = mfma16(kf, qf[1][c], s[1][t]);
            }
        }
        __builtin_amdgcn_s_setprio(0);

        // in-lane online softmax (log2 domain)
        float mx[2];
        #pragma unroll
        for (int qt = 0; qt < 2; qt++) {
            float a = fmaxf(vmax4(s[qt][0]), vmax4(s[qt][1]));
            float b = fmaxf(vmax4(s[qt][2]), vmax4(s[qt][3]));
            float v = fmaxf(a, b);
            v = fmaxf(v, __shfl_xor(v, 16));
            v = fmaxf(v, __shfl_xor(v, 32));
            mx[qt] = v;
        }
        float dmax = fmaxf(mx[0] - m[0], mx[1] - m[1]);
        if (__any(dmax > DEFER_THR)) {
            #pragma unroll
            for (int qt = 0; qt < 2; qt++) {
                float mn = fmaxf(m[qt], mx[qt]);
                float al = __builtin_amdgcn_exp2f(m[qt] - mn);
                l[qt] *= al;
                #pragma unroll
                for (int c = 0; c < 4; c++)
                    #pragma unroll
                    for (int i = 0; i < 4; i++) oacc[qt][c][i] *= al;
                m[qt] = mn;
            }
        }
        float p[2][4][4];
        #pragma unroll
        for (int qt = 0; qt < 2; qt++) {
            float ks = 0.f;
            #pragma unroll
            for (int t = 0; t < 4; t++)
                #pragma unroll
                for (int i = 0; i < 4; i++) {
                    float e = __builtin_amdgcn_exp2f(s[qt][t][i] - m[qt]);
                    p[qt][t][i] = e;
                    ks += e;
                }
            ks += __shfl_xor(ks, 16);
            ks += __shfl_xor(ks, 32);
            l[qt] += ks;
        }

        // pack P -> B-frags (pure in-lane; key slot g*8+e maps to p[2u+(e>>2)][e&3])
        bf16x8 pb[2][2];
        #pragma unroll
        for (int qt = 0; qt < 2; qt++)
            #pragma unroll
            for (int u = 0; u < 2; u++) {
                bf16x8 t8;
                #pragma unroll
                for (int e = 0; e < 4; e++) {
                    t8[e]     = (bf16_t)p[qt][2 * u][e];
                    t8[4 + e] = (bf16_t)p[qt][2 * u + 1][e];
                }
                pb[qt][u] = t8;
            }

        // O^T += V^T P^T (Vt time-permuted so A-frag is one contiguous b128)
        __builtin_amdgcn_s_setprio(1);
        #pragma unroll
        for (int c = 0; c < 4; c++)
            #pragma unroll
            for (int u = 0; u < 2; u++) {
                bf16x8 vf = *(const bf16x8*)(Vh + (c * 16 + qi) * 4096 + kt + u * 32 + g * 8);
                oacc[0][c] = mfma16(vf, pb[0][u], oacc[0][c]);
                oacc[1][c] = mfma16(vf, pb[1][u], oacc[1][c]);
            }
        __builtin_amdgcn_s_setprio(0);

        __syncthreads();
    }

    if (gridDim.z == 1) {
        #pragma unroll
        for (int qt = 0; qt < 2; qt++) {
            float inv = 1.0f / l[qt];
            int q = q0 + qt * 16 + qi;
            #pragma unroll
            for (int c = 0; c < 4; c++)
                #pragma unroll
                for (int i = 0; i < 4; i++)
                    Cb[q * 512 + h * 64 + c * 16 + g * 4 + i] = (bf16_t)(oacc[qt][c][i] * inv);
        }
    } else {
        #pragma unroll
        for (int qt = 0; qt < 2; qt++) {
            int q = q0 + qt * 16 + qi;
            float* Op = Opart + ((size_t)(split * 8 + h) * 4096 + q) * 64;
            #pragma unroll
            for (int c = 0; c < 4; c++)
                #pragma unroll
                for (int i = 0; i < 4; i++)
                    Op[c * 16 + g * 4 + i] = oacc[qt][c][i];
            if (g == 0) {
                float* mlp = MLpart + ((size_t)(split * 8 + h) * 4096 + q) * 2;
                mlp[0] = m[qt];
                mlp[1] = l[qt];
            }
        }
    }
}

// combine 2 key-splits (m in log2 domain)
__global__ void k_merge(const float* __restrict__ Opart, const float* __restrict__ MLpart,
                        bf16_t* __restrict__ Cb) {
    int idx = blockIdx.x * 256 + threadIdx.x;   // 4096*512
    int q = idx >> 9, hv = idx & 511;
    int h = hv >> 6, dv = hv & 63;
    const float* ml0 = MLpart + ((size_t)h * 4096 + q) * 2;
    const float* ml1 = MLpart + ((size_t)(8 + h) * 4096 + q) * 2;
    float m0 = ml0[0], l0 = ml0[1];
    float m1 = ml1[0], l1 = ml1[1];
    float M = fmaxf(m0, m1);
    float e0 = __builtin_amdgcn_exp2f(m0 - M);
    float e1 = __builtin_amdgcn_exp2f(m1 - M);
    float O0 = Opart[((size_t)h * 4096 + q) * 64 + dv];
    float O1 = Opart[((size_t)(8 + h) * 4096 + q) * 64 + dv];
    Cb[q * 512 + hv] = (bf16_t)((O0 * e0 + O1 * e1) / (l0 * e0 + l1 * e1));
}

// ---------------- output projection ----------------
__global__ __launch_bounds__(256) void k_gemm_out(
        const bf16_t* __restrict__ Cb, const bf16_t* __restrict__ Wot,
        const float* __restrict__ bo, float* __restrict__ out) {
    int lane = threadIdx.x & 63, wv = threadIdx.x >> 6;
    int rbase = blockIdx.x * 128 + wv * 32;
    int cbase = blockIdx.y * 64;
    int row = lane & 15, g = lane >> 4;

    const bf16_t* ap = Cb + (rbase + row) * 512 + g * 8;
    const bf16_t* bp = Wot + (cbase + row) * 512 + g * 8;
    f32x4 acc[2][4];
    #pragma unroll
    for (int at = 0; at < 2; at++)
        #pragma unroll
        for (int cc = 0; cc < 4; cc++) acc[at][cc] = (f32x4){0.f,0.f,0.f,0.f};
    #pragma unroll 4
    for (int kk = 0; kk < 512; kk += 32) {
        bf16x8 a0 = *(const bf16x8*)(ap + kk);
        bf16x8 a1 = *(const bf16x8*)(ap + 16 * 512 + kk);
        #pragma unroll
        for (int cc = 0; cc < 4; cc++) {
            bf16x8 b = *(const bf16x8*)(bp + cc * 16 * 512 + kk);
            acc[0][cc] = mfma16(a0, b, acc[0][cc]);
            acc[1][cc] = mfma16(a1, b, acc[1][cc]);
        }
    }

    #pragma unroll
    for (int cc = 0; cc < 4; cc++) {
        float bias = bo[cbase + cc * 16 + row];
        #pragma unroll
        for (int at = 0; at < 2; at++)
            #pragma unroll
            for (int i = 0; i < 4; i++)
                out[(rbase + at * 16 + g * 4 + i) * 512 + cbase + cc * 16 + row] =
                    acc[at][cc][i] + bias;
    }
}

// ---------------- launch ----------------
extern "C" void kernel_launch(void* const* d_in, const int* in_sizes, int n_in,
                              void* d_out, int out_size, void* d_ws, size_t ws_size,
                              hipStream_t stream) {
    const float* x  = (const float*)d_in[0];
    const float* Wq = (const float*)d_in[1];
    const float* bq = (const float*)d_in[2];
    const float* Wk = (const float*)d_in[3];
    const float* bk = (const float*)d_in[4];
    const float* Wv = (const float*)d_in[5];
    const float* bv = (const float*)d_in[6];
    const float* Wo = (const float*)d_in[7];
    const float* bo = (const float*)d_in[8];
    float* out = (float*)d_out;

    char* ws = (char*)d_ws;
    bf16_t* xb    = (bf16_t*)(ws + 0);          // 4,194,304
    bf16_t* Wcat  = (bf16_t*)(ws + 4194304);    // 2,621,440
    bf16_t* Qb    = (bf16_t*)(ws + 6815744);    // 8,388,608
    bf16_t* Kb    = (bf16_t*)(ws + 15204352);   // 8,388,608
    bf16_t* Vt    = (bf16_t*)(ws + 23592960);   // 4,194,304 (time-permuted)
    bf16_t* Cb    = (bf16_t*)(ws + 27787264);   // 4,194,304
    bf16_t* Wot   = (bf16_t*)(ws + 31981568);   // 524,288
    float*  bcat  = (float*)(ws + 32505856);    // 10,240
    float*  Opart = (float*)(ws + 32516096);    // 16,777,216
    float*  MLprt = (float*)(ws + 49293312);    // 524,288
    const size_t NEED2 = 49817600;
    int splits = (ws_size >= NEED2) ? 2 : 1;

    hipLaunchKernelGGL(k_stage_x,    dim3(2048),   dim3(256), 0, stream, x, xb);
    hipLaunchKernelGGL(k_stage_wt,   dim3(128, 3), dim3(256), 0, stream, Wq, Wk, Wv, Wcat);
    hipLaunchKernelGGL(k_stage_bias, dim3(10),     dim3(256), 0, stream, bq, bk, bv, bcat);
    hipLaunchKernelGGL(k_stage_wo_t, dim3(8, 8),   dim3(256), 0, stream, Wo, Wot);
    hipLaunchKernelGGL(k_gemm_qkv,   dim3(32, 40), dim3(256), 0, stream, xb, Wcat, bcat, Qb, Kb, Vt);
    hipLaunchKernelGGL(k_attn,       dim3(32, 8, splits), dim3(256), 0, stream, Qb, Kb, Vt, Cb, Opart, MLprt, 4096 / splits);
    if (splits == 2)
        hipLaunchKernelGGL(k_merge,  dim3(8192),   dim3(256), 0, stream, Opart, MLprt, Cb);
    hipLaunchKernelGGL(k_gemm_out,   dim3(32, 8),  dim3(256), 0, stream, Cb, Wot, bo, out);
}